// Round 16
// baseline (450.294 us; speedup 1.0000x reference)
//
#include <hip/hip_runtime.h>
#include <hip/hip_bf16.h>
#include <stdint.h>
#include <math.h>

#define NN   100000
#define EE   3200000
#define FIN  5
#define SHD  32
#define NH   8
#define TCH  21
#define TRH  22
#define SEQL 14

#define NPB   98
#define FPC   64
#define NC    16
#define NBUK  (NC * FPC)
#define CSZ   (NPB * FPC)
#define CAP   3712
#define CAPG1 208896
#define BCHK  4096
#define NBC1  ((EE + BCHK - 1) / BCHK)
#define PB2   ((CAPG1 + BCHK - 1) / BCHK)

typedef __hip_bfloat16 bf16;
typedef __attribute__((ext_vector_type(2))) float f32x2;

__device__ __forceinline__ float b2f(bf16 v) { return __bfloat162float(v); }
__device__ __forceinline__ float sigm(float x) { return 1.f / (1.f + __expf(-x)); }
__device__ __forceinline__ float ldw(const void* p, int i, int f) {
    return f ? ((const float*)p)[i] : __bfloat162float(((const bf16*)p)[i]);
}
__device__ __forceinline__ float relu_nan(float v) {
    return (v == v) ? ((v > 0.f) ? v : 0.f) : v;
}
__device__ __forceinline__ unsigned short f2b(float v) {
    bf16 b = __float2bfloat16(v);
    return *reinterpret_cast<unsigned short*>(&b);
}
__device__ __forceinline__ void cp(float* dst, const void* src, int n,
                                   int t0, int stride, int f) {
    if (f) {
        const float* s = (const float*)src;
        for (int i = t0; i < n; i += stride) dst[i] = s[i];
    } else {
        const bf16* s = (const bf16*)src;
        for (int i = t0; i < n; i += stride) dst[i] = b2f(s[i]);
    }
}
__device__ __forceinline__ void cpsum(float* dst, const void* s1, const void* s2,
                                      int n, int t0, int stride, int f) {
    if (f) {
        const float* a = (const float*)s1; const float* b = (const float*)s2;
        for (int i = t0; i < n; i += stride) dst[i] = a[i] + b[i];
    } else {
        const bf16* a = (const bf16*)s1; const bf16* b = (const bf16*)s2;
        for (int i = t0; i < n; i += stride) dst[i] = b2f(a[i]) + b2f(b[i]);
    }
}

// ---- dtype detect + f32 param pre-convert (identifier-named, 1 wave) ------
__global__ void PatternAwareSTGAT_94489281309_kernel(const unsigned int* xw, int* flag,
        const void* as0, const void* b0, const void* as1, const void* b1,
        const void* as2, const void* b2, float* prm) {
    int tid = threadIdx.x;   // 64
    int sane = 0;
    for (int i = 0; i < 64; i++) {
        unsigned int lo = xw[i] & 0xFFFFu;
        int e = (int)((lo >> 7) & 0xFF);
        if (e >= 110 && e <= 135) sane++;
    }
    int f = (sane >= 32) ? 0 : 1;
    if (tid == 0) flag[0] = f;
    const void* asp[3] = {as0, as1, as2};
    const void* bp[3]  = {b0, b1, b2};
    for (int l = 0; l < 3; l++)
        prm[l * 64 + tid] = (tid < 32) ? ldw(asp[l], tid, f) : ldw(bp[l], tid - 32, f);
}

// ---------------- CSR build: two-level LDS-staged counting sort --------------
__global__ __launch_bounds__(256) void k_p1(const int* __restrict__ ei,
                                            int* __restrict__ g1,
                                            int* __restrict__ rec1) {
    __shared__ int stage[BCHK];
    __shared__ int c16[NC], o16[NC], go[NC], sb[NC];
    int tid = threadIdx.x;
    if (tid < NC) c16[tid] = 0;
    __syncthreads();
    int e0 = blockIdx.x * BCHK;
    int e1 = e0 + BCHK; if (e1 > EE) e1 = EE;
    for (int e = e0 + tid; e < e1; e += 256) {
        int d = __builtin_nontemporal_load(ei + EE + e);
        atomicAdd(&c16[d / CSZ], 1);
    }
    __syncthreads();
    if (tid == 0) {
        int acc = 0;
        for (int g = 0; g < NC; g++) { sb[g] = acc; o16[g] = acc; acc += c16[g]; }
    }
    __syncthreads();
    if (tid < NC) go[tid] = (c16[tid] > 0) ? atomicAdd(&g1[tid], c16[tid]) : 0;
    __syncthreads();
    for (int e = e0 + tid; e < e1; e += 256) {
        int s = __builtin_nontemporal_load(ei + e);
        int d = __builtin_nontemporal_load(ei + EE + e);
        int g = d / CSZ;
        int p = atomicAdd(&o16[g], 1);
        stage[p] = s | ((d - g * CSZ) << 17);
    }
    __syncthreads();
    for (int g = 0; g < NC; g++) {
        int cnt = c16[g], base = go[g], sbase = sb[g];
        int* out = rec1 + (size_t)g * CAPG1;
        for (int i = tid; i < cnt; i += 256) {
            int p = base + i;
            if (p < CAPG1) out[p] = stage[sbase + i];
        }
    }
}

__global__ __launch_bounds__(256) void k_p2(const int* __restrict__ rec1,
                                            const int* __restrict__ g1,
                                            int* __restrict__ g2,
                                            int* __restrict__ rec2) {
    __shared__ int stage[BCHK];
    __shared__ int cF[FPC], oF[FPC], goF[FPC], sbF[FPC];
    int tid = threadIdx.x;
    int g = blockIdx.x / PB2;
    int c = blockIdx.x - g * PB2;
    int cnt_g = g1[g]; if (cnt_g > CAPG1) cnt_g = CAPG1;
    int i0 = c * BCHK;
    int i1 = i0 + BCHK; if (i1 > cnt_g) i1 = cnt_g;
    if (i0 >= i1) return;
    if (tid < FPC) cF[tid] = 0;
    __syncthreads();
    const int* base = rec1 + (size_t)g * CAPG1;
    for (int i = i0 + tid; i < i1; i += 256) {
        int r = base[i];
        atomicAdd(&cF[(r >> 17) / NPB], 1);
    }
    __syncthreads();
    if (tid == 0) {
        int acc = 0;
        for (int f2 = 0; f2 < FPC; f2++) { sbF[f2] = acc; oF[f2] = acc; acc += cF[f2]; }
    }
    __syncthreads();
    if (tid < FPC) goF[tid] = (cF[tid] > 0) ? atomicAdd(&g2[g * FPC + tid], cF[tid]) : 0;
    __syncthreads();
    for (int i = i0 + tid; i < i1; i += 256) {
        int r = base[i];
        int p = atomicAdd(&oF[(r >> 17) / NPB], 1);
        stage[p] = r;
    }
    __syncthreads();
    for (int f2 = 0; f2 < FPC; f2++) {
        int cnt = cF[f2], b0 = goF[f2], sb0 = sbF[f2];
        int* out = rec2 + ((size_t)(g * FPC + f2)) * CAP;
        for (int i = tid; i < cnt; i += 256) {
            int p = b0 + i;
            if (p < CAP) out[p] = stage[sb0 + i];
        }
    }
}

__global__ __launch_bounds__(256) void k_build(const int* __restrict__ rec2,
                                               const int* __restrict__ g2,
                                               int* __restrict__ csr,
                                               int* __restrict__ rstart,
                                               int* __restrict__ rdeg) {
    __shared__ int lrec[CAP];
    __shared__ int lcsr[CAP];
    __shared__ int deg[NPB], pos[NPB + 1], pos2[NPB];
    int tid = threadIdx.x;
    int b = blockIdx.x;
    int f = b & (FPC - 1);
    int fbase = f * NPB;
    int cnt = g2[b]; if (cnt > CAP) cnt = CAP;
    for (int i = tid; i < cnt; i += 256) lrec[i] = rec2[(size_t)b * CAP + i];
    if (tid < NPB) deg[tid] = 0;
    __syncthreads();
    for (int i = tid; i < cnt; i += 256) atomicAdd(&deg[(lrec[i] >> 17) - fbase], 1);
    __syncthreads();
    if (tid == 0) {
        int acc = 0;
        for (int j = 0; j < NPB; j++) { pos[j] = acc; acc += deg[j]; }
        pos[NPB] = acc;
    }
    __syncthreads();
    int nbase = b * NPB;
    if (tid < NPB) {
        pos2[tid] = pos[tid];
        int n = nbase + tid;
        if (n < NN) { rstart[n] = b * CAP + pos[tid]; rdeg[n] = deg[tid]; }
    }
    __syncthreads();
    for (int i = tid; i < cnt; i += 256) {
        int r = lrec[i];
        int p = atomicAdd(&pos2[(r >> 17) - fbase], 1);
        lcsr[p] = r & 0x1FFFF;
    }
    __syncthreads();
    for (int i = tid; i < cnt; i += 256) csr[(size_t)b * CAP + i] = lcsr[i];
}

// ---------------- GAT transform (layer 0: raw input, DIN=5) ----------------
__global__ void k_transform0(const void* x, const void* W, const void* ad_,
                             const int* flag, unsigned short* hWb, float* ed) {
    __shared__ float sW[FIN * SHD];
    __shared__ float sad[SHD];
    int tid = threadIdx.x;
    int f = flag[0];
    cp(sW, W, FIN * SHD, tid, 256, f);
    if (tid >= 192 && tid < 192 + SHD) sad[tid - 192] = ldw(ad_, tid - 192, f);
    __syncthreads();
    int n = blockIdx.x * 256 + tid;
    if (n >= NN) return;
    float xr[FIN];
    if (f) {
        const float* xp = (const float*)x + (size_t)n * FIN;
        for (int k = 0; k < FIN; k++) xr[k] = xp[k];
    } else {
        const bf16* xp = (const bf16*)x + (size_t)n * FIN;
        for (int k = 0; k < FIN; k++) xr[k] = b2f(xp[k]);
    }
    float o[SHD];
    for (int j = 0; j < SHD; j++) o[j] = 0.f;
    for (int k = 0; k < FIN; k++) {
        float xv = xr[k];
        for (int j = 0; j < SHD; j++) o[j] += xv * sW[k * SHD + j];
    }
    ushort4* row = (ushort4*)(hWb + (size_t)n * SHD);
    for (int q = 0; q < 8; q++) {
        ushort4 v; v.x = f2b(o[q*4]); v.y = f2b(o[q*4+1]); v.z = f2b(o[q*4+2]); v.w = f2b(o[q*4+3]);
        row[q] = v;
    }
    for (int h = 0; h < NH; h++) {
        float e2 = 0.f;
        for (int c = 0; c < 4; c++) e2 += o[h * 4 + c] * sad[h * 4 + c];
        ed[(size_t)n * NH + h] = e2;
    }
}

// ---------------- GAT transform (layers 1/2: f32 ws input, DIN=32) ----------
__global__ void k_transform1(const float* x, const void* W, const void* ad_,
                             const int* flag, unsigned short* hWb, float* ed) {
    __shared__ float sW[SHD * SHD];
    __shared__ float sad[SHD];
    int tid = threadIdx.x;
    int f = flag[0];
    cp(sW, W, SHD * SHD, tid, 256, f);
    if (tid >= 192 && tid < 192 + SHD) sad[tid - 192] = ldw(ad_, tid - 192, f);
    __syncthreads();
    int n = blockIdx.x * 256 + tid;
    if (n >= NN) return;
    float xr[SHD];
    for (int k = 0; k < SHD; k++) xr[k] = x[(size_t)n * SHD + k];
    float o[SHD];
    for (int j = 0; j < SHD; j++) o[j] = 0.f;
    for (int k = 0; k < SHD; k++) {
        float xv = xr[k];
        for (int j = 0; j < SHD; j++) o[j] += xv * sW[k * SHD + j];
    }
    ushort4* row = (ushort4*)(hWb + (size_t)n * SHD);
    for (int q = 0; q < 8; q++) {
        ushort4 v; v.x = f2b(o[q*4]); v.y = f2b(o[q*4+1]); v.z = f2b(o[q*4+2]); v.w = f2b(o[q*4+3]);
        row[q] = v;
    }
    for (int h = 0; h < NH; h++) {
        float e2 = 0.f;
        for (int c = 0; c < 4; c++) e2 += o[h * 4 + c] * sad[h * 4 + c];
        ed[(size_t)n * NH + h] = e2;
    }
}

// ---------------- GAT aggregation: 2 nodes/wave, 2-deep pipelined gather ----
__global__ void k_aggregate(const int* __restrict__ rstart, const int* __restrict__ rdeg,
                            const int* __restrict__ csr,
                            const unsigned short* __restrict__ hWb,
                            const float* __restrict__ ed,
                            const float* __restrict__ prm,
                            float* __restrict__ out) {
    int gid = blockIdx.x * 256 + threadIdx.x;
    int lane = threadIdx.x & 63;
    int n = (gid >> 6) * 2 + (lane >> 5);
    if (n >= NN) return;
    int l32 = lane & 31;
    int h = l32 & 7, k = l32 >> 3;
    float4 asv = *(const float4*)(prm + h * 4);
    float ednh = ed[(size_t)n * NH + h];
    int base = rstart[n];
    int deg = rdeg[n];
    float den = 0.f;
    f32x2 acc01 = {0.f, 0.f}, acc23 = {0.f, 0.f};
    int t = k;
    int sA = -1, sB = -1;
    if (t <= deg) sA = (t == 0) ? n : __builtin_nontemporal_load(csr + base + t - 1);
    if (t + 4 <= deg) sB = __builtin_nontemporal_load(csr + base + t + 3);
    while (sA >= 0) {
        uint2 hvA = *(const uint2*)(hWb + (size_t)sA * SHD + h * 4);
        bool hasB = (sB >= 0);
        uint2 hvB;
        if (hasB) hvB = *(const uint2*)(hWb + (size_t)sB * SHD + h * 4);
        int tn = t + 8;
        int sC = -1, sD = -1;
        if (tn <= deg) sC = __builtin_nontemporal_load(csr + base + tn - 1);
        if (tn + 4 <= deg) sD = __builtin_nontemporal_load(csr + base + tn + 3);
        {
            f32x2 h01, h23;
            h01.x = __uint_as_float(hvA.x << 16);
            h01.y = __uint_as_float(hvA.x & 0xffff0000u);
            h23.x = __uint_as_float(hvA.y << 16);
            h23.y = __uint_as_float(hvA.y & 0xffff0000u);
            f32x2 d2 = h01 * (f32x2){asv.x, asv.y} + h23 * (f32x2){asv.z, asv.w};
            float e = d2.x + d2.y + ednh;
            e = fmaxf(e, 0.2f * e);
            float a = __expf(e);
            den += a;
            f32x2 av = {a, a};
            acc01 += av * h01;
            acc23 += av * h23;
        }
        if (hasB) {
            f32x2 h01, h23;
            h01.x = __uint_as_float(hvB.x << 16);
            h01.y = __uint_as_float(hvB.x & 0xffff0000u);
            h23.x = __uint_as_float(hvB.y << 16);
            h23.y = __uint_as_float(hvB.y & 0xffff0000u);
            f32x2 d2 = h01 * (f32x2){asv.x, asv.y} + h23 * (f32x2){asv.z, asv.w};
            float e = d2.x + d2.y + ednh;
            e = fmaxf(e, 0.2f * e);
            float a = __expf(e);
            den += a;
            f32x2 av = {a, a};
            acc01 += av * h01;
            acc23 += av * h23;
        }
        sA = sC; sB = sD; t = tn;
    }
    for (int off = 16; off >= 8; off >>= 1) {
        den      += __shfl_down(den, off, 32);
        acc01.x  += __shfl_down(acc01.x, off, 32);
        acc01.y  += __shfl_down(acc01.y, off, 32);
        acc23.x  += __shfl_down(acc23.x, off, 32);
        acc23.y  += __shfl_down(acc23.y, off, 32);
    }
    if (k == 0) {
        float inv = 1.f / (den + 1e-16f);
        float4 bv = *(const float4*)(prm + 32 + h * 4);
        float v0 = acc01.x * inv + bv.x;
        float v1 = acc01.y * inv + bv.y;
        float v2 = acc23.x * inv + bv.z;
        float v3 = acc23.y * inv + bv.w;
        v0 = (v0 > 0.f) ? v0 : expm1f(v0);
        v1 = (v1 > 0.f) ? v1 : expm1f(v1);
        v2 = (v2 > 0.f) ? v2 : expm1f(v2);
        v3 = (v3 > 0.f) ? v3 : expm1f(v3);
        *(float4*)(out + (size_t)n * SHD + h * 4) = make_float4(v0, v1, v2, v3);
    }
}

// ---------------- Temporal tail ----------------
// __launch_bounds__(256, 1): r15's VGPR_Count=64 proves the per-lane LSTM
// weight arrays (84+48 floats) spilled to scratch — the 55us was serial
// scratch reloads in the recurrence. 1 wave/EU allows up to ~512 VGPRs.
__global__ __launch_bounds__(256, 1)
void k_tail(const void* trend, const void* seasonal, const void* residual,
                       const void* cv, const int* tgtp,
                       const void* tWih0, const void* tWhh0, const void* tbih0, const void* tbhh0,
                       const void* tWih1, const void* tWhh1, const void* tbih1, const void* tbhh1,
                       const void* sWih0, const void* sWhh0, const void* sbih0, const void* sbhh0,
                       const void* sWih1, const void* sWhh1, const void* sbih1, const void* sbhh1,
                       const void* res_W, const void* res_b,
                       const void* pg_W, const void* pg_b,
                       const void* f1_W, const void* f1_b,
                       const void* ln_g, const void* ln_b,
                       const void* f2_W, const void* f2_b,
                       const void* f3_W, const void* f3_b,
                       const int* flag, const float* A, void* out) {
    __shared__ float smem[11088];
    __shared__ float shh[2][24];
    __shared__ float sseq[2][SEQL][24];
    __shared__ float sx[2][SEQL];
    __shared__ float comb[97], gf[96], h1[64], h2s[32], stats[2];
    int tid = threadIdx.x;
    int f = flag[0];
    int w = tid >> 6, l = tid & 63;
    float* pk0a = smem;
    float* pk0b = smem + 1932;
    float* pk1a = smem + 3864;
    float* pk1b = smem + 7476;

    cp(pk0a, tWih0, 84, tid, 256, f);
    cp(pk0a + 84, tWhh0, 1764, tid, 256, f);
    cpsum(pk0a + 1848, tbih0, tbhh0, 84, tid, 256, f);
    cp(pk0b, sWih0, 84, tid, 256, f);
    cp(pk0b + 84, sWhh0, 1764, tid, 256, f);
    cpsum(pk0b + 1848, sbih0, sbhh0, 84, tid, 256, f);
    if (tid < 2 * SEQL) sx[tid / SEQL][tid % SEQL] = (tid < SEQL) ? ldw(trend, tid, f)
                                                                  : ldw(seasonal, tid - SEQL, f);
    if (tid < 48) shh[tid / 24][tid % 24] = 0.f;
    for (int i = tid; i < 2 * SEQL * 24; i += 256) ((float*)sseq)[i] = 0.f;
    __syncthreads();

    if (w < 2) {
        const float* P = (w == 0) ? pk0a : pk0b;
        float* SH = shh[w];
        float wa = P[l], ba = P[1848 + l];
        float wb = (l < 20) ? P[64 + l] : 0.f;
        float bb = (l < 20) ? P[1848 + 64 + l] : 0.f;
        float Wa[21], Wb[21];
#pragma unroll
        for (int j = 0; j < 21; j++) {
            Wa[j] = P[84 + l * 21 + j];
            Wb[j] = (l < 20) ? P[84 + (64 + l) * 21 + j] : 0.f;
        }
        float h = 0.f, c = 0.f;
#pragma unroll
        for (int t = 0; t < SEQL; t++) {
            float xt = sx[w][t];
            float acc_a = ba + xt * wa;
            float acc_b = bb + xt * wb;
            float hb[24];
#pragma unroll
            for (int q = 0; q < 6; q++) {
                float4 v = *(const float4*)&SH[q * 4];
                hb[q*4] = v.x; hb[q*4+1] = v.y; hb[q*4+2] = v.z; hb[q*4+3] = v.w;
            }
#pragma unroll
            for (int j = 0; j < 21; j++) { acc_a += hb[j] * Wa[j]; acc_b += hb[j] * Wb[j]; }
            float fj = __shfl(acc_a, 21 + l);
            float gj = __shfl(acc_a, 42 + l);
            float oa = __shfl(acc_a, 63);
            float ob = __shfl(acc_b, (l == 0) ? 0 : (l - 1));
            float oj = (l == 0) ? oa : ob;
            if (l < 21) {
                float iv = sigm(acc_a), fv = sigm(fj);
                float gv = tanhf(gj), ov = sigm(oj);
                c = fv * c + iv * gv;
                h = ov * tanhf(c);
                SH[l] = h;
                sseq[w][t][l] = h;
            }
            __threadfence_block();
        }
    } else {
        int t2 = tid - 128;
        cp(pk1a, tWih1, 1764, t2, 128, f);
        cp(pk1a + 1764, tWhh1, 1764, t2, 128, f);
        cpsum(pk1a + 3528, tbih1, tbhh1, 84, t2, 128, f);
        cp(pk1b, sWih1, 1764, t2, 128, f);
        cp(pk1b + 1764, sWhh1, 1764, t2, 128, f);
        cpsum(pk1b + 3528, sbih1, sbhh1, 84, t2, 128, f);
    }
    __syncthreads();
    if (tid < 48) shh[tid / 24][tid % 24] = 0.f;
    __syncthreads();

    if (w < 2) {
        const float* P = (w == 0) ? pk1a : pk1b;
        float* SH = shh[w];
        float ba = P[3528 + l];
        float bb = (l < 20) ? P[3528 + 64 + l] : 0.f;
        float Ua[21], Va[21], Ub[21], Vb[21];
#pragma unroll
        for (int j = 0; j < 21; j++) {
            Ua[j] = P[l * 21 + j];
            Va[j] = P[1764 + l * 21 + j];
            Ub[j] = (l < 20) ? P[(64 + l) * 21 + j] : 0.f;
            Vb[j] = (l < 20) ? P[1764 + (64 + l) * 21 + j] : 0.f;
        }
        float h = 0.f, c = 0.f;
#pragma unroll
        for (int t = 0; t < SEQL; t++) {
            float acc_a = ba, acc_b = bb;
            float hb[24], xb[24];
#pragma unroll
            for (int q = 0; q < 6; q++) {
                float4 v = *(const float4*)&SH[q * 4];
                hb[q*4] = v.x; hb[q*4+1] = v.y; hb[q*4+2] = v.z; hb[q*4+3] = v.w;
                float4 u = *(const float4*)&sseq[w][t][q * 4];
                xb[q*4] = u.x; xb[q*4+1] = u.y; xb[q*4+2] = u.z; xb[q*4+3] = u.w;
            }
#pragma unroll
            for (int j = 0; j < 21; j++) {
                acc_a += xb[j] * Ua[j] + hb[j] * Va[j];
                acc_b += xb[j] * Ub[j] + hb[j] * Vb[j];
            }
            float fj = __shfl(acc_a, 21 + l);
            float gj = __shfl(acc_a, 42 + l);
            float oa = __shfl(acc_a, 63);
            float ob = __shfl(acc_b, (l == 0) ? 0 : (l - 1));
            float oj = (l == 0) ? oa : ob;
            if (l < 21) {
                float iv = sigm(acc_a), fv = sigm(fj);
                float gv = tanhf(gj), ov = sigm(oj);
                c = fv * c + iv * gv;
                h = ov * tanhf(c);
                SH[l] = h;
            }
            __threadfence_block();
        }
        if (l < 21) comb[(w == 0 ? 32 : 53) + l] = h;
    }
    __syncthreads();

    int tgt = tgtp[0];
    if (tid >= 64 && tid < 64 + TRH) {
        int j = tid - 64;
        float v = ldw(residual, SEQL - 1, f) * ldw(res_W, j, f) + ldw(res_b, j, f);
        comb[74 + j] = relu_nan(v);
    }
    if (tid >= 192 && tid < 192 + SHD) comb[tid - 192] = A[(size_t)tgt * SHD + (tid - 192)];
    if (tid == 90) comb[96] = ldw(cv, 0, f);
    cp(smem, pg_W, 97 * 96, tid, 256, f);
    __syncthreads();
    if (tid < 96) {
        float acc = ldw(pg_b, tid, f);
        for (int k2 = 0; k2 < 97; k2++) acc += comb[k2] * smem[k2 * 96 + tid];
        gf[tid] = comb[tid] * sigm(acc);
    }
    __syncthreads();
    cp(smem, f1_W, 96 * 64, tid, 256, f);
    __syncthreads();
    if (tid < 64) {
        float acc = ldw(f1_b, tid, f);
        for (int k2 = 0; k2 < 96; k2++) acc += gf[k2] * smem[k2 * 64 + tid];
        h1[tid] = acc;
    }
    __syncthreads();
    if (tid == 0) {
        float mu = 0.f;
        for (int j = 0; j < 64; j++) mu += h1[j];
        mu /= 64.f;
        float var = 0.f;
        for (int j = 0; j < 64; j++) { float d = h1[j] - mu; var += d * d; }
        var /= 64.f;
        stats[0] = mu; stats[1] = rsqrtf(var + 1e-5f);
    }
    cp(smem, f2_W, 64 * 32, tid, 256, f);
    cp(smem + 64 * 32, f3_W, 32 * 14, tid, 256, f);
    __syncthreads();
    if (tid < 64) {
        float v = (h1[tid] - stats[0]) * stats[1] * ldw(ln_g, tid, f) + ldw(ln_b, tid, f);
        h1[tid] = relu_nan(v);
    }
    __syncthreads();
    if (tid < 32) {
        float acc = ldw(f2_b, tid, f);
        for (int k2 = 0; k2 < 64; k2++) acc += h1[k2] * smem[k2 * 32 + tid];
        h2s[tid] = relu_nan(acc);
    }
    __syncthreads();
    if (tid < 14) {
        float acc = ldw(f3_b, tid, f);
        for (int k2 = 0; k2 < 32; k2++) acc += h2s[k2] * smem[64 * 32 + k2 * 14 + tid];
        if (acc != acc) acc = 3333.0f;
        if (f) ((float*)out)[tid] = acc;
        else   ((bf16*)out)[tid] = __float2bfloat16(acc);
    }
}

// ---------------- host helpers ----------------
static inline unsigned short h_f2bf(float f) {
    union { float f; unsigned u; } x; x.f = f;
    return (unsigned short)(x.u >> 16);
}
static unsigned short g_diag[SEQL];

// ---------------- launch ----------------
extern "C" void kernel_launch(void* const* d_in, const int* in_sizes, int n_in,
                              void* d_out, int out_size, void* d_ws, size_t ws_size,
                              hipStream_t stream) {
    const int* ei  = (const int*)d_in[1];
    const int* tgt = (const int*)d_in[6];

    const size_t HWB  = sizeof(unsigned short) * (size_t)NN * SHD;
    const size_t EDB  = sizeof(float) * (size_t)NN * NH;
    const size_t AB   = sizeof(float) * (size_t)NN * SHD;
    const size_t CSRB = sizeof(int) * (size_t)NBUK * CAP;
    const size_t NEED = 256 + 1024 + sizeof(int) * (size_t)(NC + NBUK + 2 * NN + 32)
                      + CSRB + 512 + HWB + EDB + AB;
    if (ws_size < NEED ||
        sizeof(int) * (size_t)NC * CAPG1 > CSRB ||
        sizeof(int) * (size_t)NBUK * CAP > HWB + EDB + AB) {
        for (int i = 0; i < SEQL; i++) g_diag[i] = h_f2bf(7777.0f);
        hipMemcpyAsync(d_out, g_diag, SEQL * sizeof(unsigned short),
                       hipMemcpyHostToDevice, stream);
        return;
    }

    char* p = (char*)d_ws;
    int*   flag = (int*)p;   p += 256;
    float* prm  = (float*)p; p += 1024;
    int* g1     = (int*)p; p += sizeof(int) * NC;
    int* g2     = (int*)p; p += sizeof(int) * NBUK;
    int* rstart = (int*)p; p += sizeof(int) * NN;
    int* rdeg   = (int*)p; p += sizeof(int) * (NN + 32);
    int* csr    = (int*)p; p += CSRB;
    p = (char*)(((uintptr_t)p + 255) & ~(uintptr_t)255);
    unsigned short* hWb = (unsigned short*)p; p += HWB;
    float* ed = (float*)p; p += EDB;
    float* A  = (float*)p; p += AB;
    int* rec1 = csr;
    int* rec2 = (int*)hWb;

    dim3 b256(256);
    dim3 gN((NN + 255) / 256);
    dim3 gA2(((NN + 1) / 2 * 64 + 255) / 256);

    PatternAwareSTGAT_94489281309_kernel<<<dim3(1), dim3(64), 0, stream>>>(
        (const unsigned int*)d_in[0], flag,
        d_in[8], d_in[10], d_in[12], d_in[14], d_in[16], d_in[18], prm);

    hipMemsetAsync(g1, 0, sizeof(int) * (NC + NBUK), stream);
    k_p1<<<dim3(NBC1), b256, 0, stream>>>(ei, g1, rec1);
    k_p2<<<dim3(NC * PB2), b256, 0, stream>>>(rec1, g1, g2, rec2);
    k_build<<<dim3(NBUK), b256, 0, stream>>>(rec2, g2, csr, rstart, rdeg);

    k_transform0<<<gN, b256, 0, stream>>>(d_in[0], d_in[7], d_in[9], flag, hWb, ed);
    k_aggregate<<<gA2, b256, 0, stream>>>(rstart, rdeg, csr, hWb, ed, prm, A);
    k_transform1<<<gN, b256, 0, stream>>>(A, d_in[11], d_in[13], flag, hWb, ed);
    k_aggregate<<<gA2, b256, 0, stream>>>(rstart, rdeg, csr, hWb, ed, prm + 64, A);
    k_transform1<<<gN, b256, 0, stream>>>(A, d_in[15], d_in[17], flag, hWb, ed);
    k_aggregate<<<gA2, b256, 0, stream>>>(rstart, rdeg, csr, hWb, ed, prm + 128, A);

    k_tail<<<dim3(1), b256, 0, stream>>>(
        d_in[2], d_in[3], d_in[4], d_in[5], tgt,
        d_in[19], d_in[20], d_in[21], d_in[22],
        d_in[23], d_in[24], d_in[25], d_in[26],
        d_in[27], d_in[28], d_in[29], d_in[30],
        d_in[31], d_in[32], d_in[33], d_in[34],
        d_in[35], d_in[36],
        d_in[37], d_in[38],
        d_in[39], d_in[40],
        d_in[41], d_in[42],
        d_in[43], d_in[44],
        d_in[45], d_in[46],
        flag, A, d_out);
}

// Round 17
// 450.123 us; speedup vs baseline: 1.0004x; 1.0004x over previous
//
#include <hip/hip_runtime.h>
#include <hip/hip_bf16.h>
#include <stdint.h>
#include <math.h>

#define NN   100000
#define EE   3200000
#define FIN  5
#define SHD  32
#define NH   8
#define TCH  21
#define TRH  22
#define SEQL 14

#define NPB   98
#define FPC   64
#define NC    16
#define NBUK  (NC * FPC)
#define CSZ   (NPB * FPC)
#define CAP   3712
#define CAPG1 208896
#define BCHK  4096
#define NBC1  ((EE + BCHK - 1) / BCHK)
#define PB2   ((CAPG1 + BCHK - 1) / BCHK)

typedef __hip_bfloat16 bf16;
typedef __attribute__((ext_vector_type(2))) float f32x2;

__device__ __forceinline__ float b2f(bf16 v) { return __bfloat162float(v); }
__device__ __forceinline__ float sigm(float x) { return 1.f / (1.f + __expf(-x)); }
__device__ __forceinline__ float tanh_fast(float x) {
    x = fminf(fmaxf(x, -15.f), 15.f);
    float e = __expf(2.f * x);
    return (e - 1.f) / (e + 1.f);
}
__device__ __forceinline__ float ldw(const void* p, int i, int f) {
    return f ? ((const float*)p)[i] : __bfloat162float(((const bf16*)p)[i]);
}
__device__ __forceinline__ float relu_nan(float v) {
    return (v == v) ? ((v > 0.f) ? v : 0.f) : v;
}
__device__ __forceinline__ unsigned short f2b(float v) {
    bf16 b = __float2bfloat16(v);
    return *reinterpret_cast<unsigned short*>(&b);
}
__device__ __forceinline__ void cp(float* dst, const void* src, int n,
                                   int t0, int stride, int f) {
    if (f) {
        const float* s = (const float*)src;
        for (int i = t0; i < n; i += stride) dst[i] = s[i];
    } else {
        const bf16* s = (const bf16*)src;
        for (int i = t0; i < n; i += stride) dst[i] = b2f(s[i]);
    }
}
__device__ __forceinline__ void cpsum(float* dst, const void* s1, const void* s2,
                                      int n, int t0, int stride, int f) {
    if (f) {
        const float* a = (const float*)s1; const float* b = (const float*)s2;
        for (int i = t0; i < n; i += stride) dst[i] = a[i] + b[i];
    } else {
        const bf16* a = (const bf16*)s1; const bf16* b = (const bf16*)s2;
        for (int i = t0; i < n; i += stride) dst[i] = b2f(a[i]) + b2f(b[i]);
    }
}

// ---- dtype detect + f32 param pre-convert (identifier-named, 1 wave) ------
__global__ void PatternAwareSTGAT_94489281309_kernel(const unsigned int* xw, int* flag,
        const void* as0, const void* b0, const void* as1, const void* b1,
        const void* as2, const void* b2, float* prm) {
    int tid = threadIdx.x;   // 64
    int sane = 0;
    for (int i = 0; i < 64; i++) {
        unsigned int lo = xw[i] & 0xFFFFu;
        int e = (int)((lo >> 7) & 0xFF);
        if (e >= 110 && e <= 135) sane++;
    }
    int f = (sane >= 32) ? 0 : 1;
    if (tid == 0) flag[0] = f;
    const void* asp[3] = {as0, as1, as2};
    const void* bp[3]  = {b0, b1, b2};
    for (int l = 0; l < 3; l++)
        prm[l * 64 + tid] = (tid < 32) ? ldw(asp[l], tid, f) : ldw(bp[l], tid - 32, f);
}

// ---------------- CSR build: two-level LDS-staged counting sort --------------
__global__ __launch_bounds__(256) void k_p1(const int* __restrict__ ei,
                                            int* __restrict__ g1,
                                            int* __restrict__ rec1) {
    __shared__ int stage[BCHK];
    __shared__ int c16[NC], o16[NC], go[NC], sb[NC];
    int tid = threadIdx.x;
    if (tid < NC) c16[tid] = 0;
    __syncthreads();
    int e0 = blockIdx.x * BCHK;
    int e1 = e0 + BCHK; if (e1 > EE) e1 = EE;
    for (int e = e0 + tid; e < e1; e += 256) {
        int d = __builtin_nontemporal_load(ei + EE + e);
        atomicAdd(&c16[d / CSZ], 1);
    }
    __syncthreads();
    if (tid == 0) {
        int acc = 0;
        for (int g = 0; g < NC; g++) { sb[g] = acc; o16[g] = acc; acc += c16[g]; }
    }
    __syncthreads();
    if (tid < NC) go[tid] = (c16[tid] > 0) ? atomicAdd(&g1[tid], c16[tid]) : 0;
    __syncthreads();
    for (int e = e0 + tid; e < e1; e += 256) {
        int s = __builtin_nontemporal_load(ei + e);
        int d = __builtin_nontemporal_load(ei + EE + e);
        int g = d / CSZ;
        int p = atomicAdd(&o16[g], 1);
        stage[p] = s | ((d - g * CSZ) << 17);
    }
    __syncthreads();
    for (int g = 0; g < NC; g++) {
        int cnt = c16[g], base = go[g], sbase = sb[g];
        int* out = rec1 + (size_t)g * CAPG1;
        for (int i = tid; i < cnt; i += 256) {
            int p = base + i;
            if (p < CAPG1) out[p] = stage[sbase + i];
        }
    }
}

__global__ __launch_bounds__(256) void k_p2(const int* __restrict__ rec1,
                                            const int* __restrict__ g1,
                                            int* __restrict__ g2,
                                            int* __restrict__ rec2) {
    __shared__ int stage[BCHK];
    __shared__ int cF[FPC], oF[FPC], goF[FPC], sbF[FPC];
    int tid = threadIdx.x;
    int g = blockIdx.x / PB2;
    int c = blockIdx.x - g * PB2;
    int cnt_g = g1[g]; if (cnt_g > CAPG1) cnt_g = CAPG1;
    int i0 = c * BCHK;
    int i1 = i0 + BCHK; if (i1 > cnt_g) i1 = cnt_g;
    if (i0 >= i1) return;
    if (tid < FPC) cF[tid] = 0;
    __syncthreads();
    const int* base = rec1 + (size_t)g * CAPG1;
    for (int i = i0 + tid; i < i1; i += 256) {
        int r = base[i];
        atomicAdd(&cF[(r >> 17) / NPB], 1);
    }
    __syncthreads();
    if (tid == 0) {
        int acc = 0;
        for (int f2 = 0; f2 < FPC; f2++) { sbF[f2] = acc; oF[f2] = acc; acc += cF[f2]; }
    }
    __syncthreads();
    if (tid < FPC) goF[tid] = (cF[tid] > 0) ? atomicAdd(&g2[g * FPC + tid], cF[tid]) : 0;
    __syncthreads();
    for (int i = i0 + tid; i < i1; i += 256) {
        int r = base[i];
        int p = atomicAdd(&oF[(r >> 17) / NPB], 1);
        stage[p] = r;
    }
    __syncthreads();
    for (int f2 = 0; f2 < FPC; f2++) {
        int cnt = cF[f2], b0 = goF[f2], sb0 = sbF[f2];
        int* out = rec2 + ((size_t)(g * FPC + f2)) * CAP;
        for (int i = tid; i < cnt; i += 256) {
            int p = b0 + i;
            if (p < CAP) out[p] = stage[sb0 + i];
        }
    }
}

__global__ __launch_bounds__(256) void k_build(const int* __restrict__ rec2,
                                               const int* __restrict__ g2,
                                               int* __restrict__ csr,
                                               int* __restrict__ rstart,
                                               int* __restrict__ rdeg) {
    __shared__ int lrec[CAP];
    __shared__ int lcsr[CAP];
    __shared__ int deg[NPB], pos[NPB + 1], pos2[NPB];
    int tid = threadIdx.x;
    int b = blockIdx.x;
    int f = b & (FPC - 1);
    int fbase = f * NPB;
    int cnt = g2[b]; if (cnt > CAP) cnt = CAP;
    for (int i = tid; i < cnt; i += 256) lrec[i] = rec2[(size_t)b * CAP + i];
    if (tid < NPB) deg[tid] = 0;
    __syncthreads();
    for (int i = tid; i < cnt; i += 256) atomicAdd(&deg[(lrec[i] >> 17) - fbase], 1);
    __syncthreads();
    if (tid == 0) {
        int acc = 0;
        for (int j = 0; j < NPB; j++) { pos[j] = acc; acc += deg[j]; }
        pos[NPB] = acc;
    }
    __syncthreads();
    int nbase = b * NPB;
    if (tid < NPB) {
        pos2[tid] = pos[tid];
        int n = nbase + tid;
        if (n < NN) { rstart[n] = b * CAP + pos[tid]; rdeg[n] = deg[tid]; }
    }
    __syncthreads();
    for (int i = tid; i < cnt; i += 256) {
        int r = lrec[i];
        int p = atomicAdd(&pos2[(r >> 17) - fbase], 1);
        lcsr[p] = r & 0x1FFFF;
    }
    __syncthreads();
    for (int i = tid; i < cnt; i += 256) csr[(size_t)b * CAP + i] = lcsr[i];
}

// ---------------- GAT transform (layer 0: raw input, DIN=5) ----------------
__global__ void k_transform0(const void* x, const void* W, const void* ad_,
                             const int* flag, unsigned short* hWb, float* ed) {
    __shared__ float sW[FIN * SHD];
    __shared__ float sad[SHD];
    int tid = threadIdx.x;
    int f = flag[0];
    cp(sW, W, FIN * SHD, tid, 256, f);
    if (tid >= 192 && tid < 192 + SHD) sad[tid - 192] = ldw(ad_, tid - 192, f);
    __syncthreads();
    int n = blockIdx.x * 256 + tid;
    if (n >= NN) return;
    float xr[FIN];
    if (f) {
        const float* xp = (const float*)x + (size_t)n * FIN;
        for (int k = 0; k < FIN; k++) xr[k] = xp[k];
    } else {
        const bf16* xp = (const bf16*)x + (size_t)n * FIN;
        for (int k = 0; k < FIN; k++) xr[k] = b2f(xp[k]);
    }
    float o[SHD];
    for (int j = 0; j < SHD; j++) o[j] = 0.f;
    for (int k = 0; k < FIN; k++) {
        float xv = xr[k];
        for (int j = 0; j < SHD; j++) o[j] += xv * sW[k * SHD + j];
    }
    ushort4* row = (ushort4*)(hWb + (size_t)n * SHD);
    for (int q = 0; q < 8; q++) {
        ushort4 v; v.x = f2b(o[q*4]); v.y = f2b(o[q*4+1]); v.z = f2b(o[q*4+2]); v.w = f2b(o[q*4+3]);
        row[q] = v;
    }
    for (int h = 0; h < NH; h++) {
        float e2 = 0.f;
        for (int c = 0; c < 4; c++) e2 += o[h * 4 + c] * sad[h * 4 + c];
        ed[(size_t)n * NH + h] = e2;
    }
}

// ---------------- GAT transform (layers 1/2: f32 ws input, DIN=32) ----------
__global__ void k_transform1(const float* x, const void* W, const void* ad_,
                             const int* flag, unsigned short* hWb, float* ed) {
    __shared__ float sW[SHD * SHD];
    __shared__ float sad[SHD];
    int tid = threadIdx.x;
    int f = flag[0];
    cp(sW, W, SHD * SHD, tid, 256, f);
    if (tid >= 192 && tid < 192 + SHD) sad[tid - 192] = ldw(ad_, tid - 192, f);
    __syncthreads();
    int n = blockIdx.x * 256 + tid;
    if (n >= NN) return;
    float xr[SHD];
    for (int k = 0; k < SHD; k++) xr[k] = x[(size_t)n * SHD + k];
    float o[SHD];
    for (int j = 0; j < SHD; j++) o[j] = 0.f;
    for (int k = 0; k < SHD; k++) {
        float xv = xr[k];
        for (int j = 0; j < SHD; j++) o[j] += xv * sW[k * SHD + j];
    }
    ushort4* row = (ushort4*)(hWb + (size_t)n * SHD);
    for (int q = 0; q < 8; q++) {
        ushort4 v; v.x = f2b(o[q*4]); v.y = f2b(o[q*4+1]); v.z = f2b(o[q*4+2]); v.w = f2b(o[q*4+3]);
        row[q] = v;
    }
    for (int h = 0; h < NH; h++) {
        float e2 = 0.f;
        for (int c = 0; c < 4; c++) e2 += o[h * 4 + c] * sad[h * 4 + c];
        ed[(size_t)n * NH + h] = e2;
    }
}

// ---------------- GAT aggregation: 2 nodes/wave, 2-deep pipelined gather ----
__global__ void k_aggregate(const int* __restrict__ rstart, const int* __restrict__ rdeg,
                            const int* __restrict__ csr,
                            const unsigned short* __restrict__ hWb,
                            const float* __restrict__ ed,
                            const float* __restrict__ prm,
                            float* __restrict__ out) {
    int gid = blockIdx.x * 256 + threadIdx.x;
    int lane = threadIdx.x & 63;
    int n = (gid >> 6) * 2 + (lane >> 5);
    if (n >= NN) return;
    int l32 = lane & 31;
    int h = l32 & 7, k = l32 >> 3;
    float4 asv = *(const float4*)(prm + h * 4);
    float ednh = ed[(size_t)n * NH + h];
    int base = rstart[n];
    int deg = rdeg[n];
    float den = 0.f;
    f32x2 acc01 = {0.f, 0.f}, acc23 = {0.f, 0.f};
    int t = k;
    int sA = -1, sB = -1;
    if (t <= deg) sA = (t == 0) ? n : __builtin_nontemporal_load(csr + base + t - 1);
    if (t + 4 <= deg) sB = __builtin_nontemporal_load(csr + base + t + 3);
    while (sA >= 0) {
        uint2 hvA = *(const uint2*)(hWb + (size_t)sA * SHD + h * 4);
        bool hasB = (sB >= 0);
        uint2 hvB;
        if (hasB) hvB = *(const uint2*)(hWb + (size_t)sB * SHD + h * 4);
        int tn = t + 8;
        int sC = -1, sD = -1;
        if (tn <= deg) sC = __builtin_nontemporal_load(csr + base + tn - 1);
        if (tn + 4 <= deg) sD = __builtin_nontemporal_load(csr + base + tn + 3);
        {
            f32x2 h01, h23;
            h01.x = __uint_as_float(hvA.x << 16);
            h01.y = __uint_as_float(hvA.x & 0xffff0000u);
            h23.x = __uint_as_float(hvA.y << 16);
            h23.y = __uint_as_float(hvA.y & 0xffff0000u);
            f32x2 d2 = h01 * (f32x2){asv.x, asv.y} + h23 * (f32x2){asv.z, asv.w};
            float e = d2.x + d2.y + ednh;
            e = fmaxf(e, 0.2f * e);
            float a = __expf(e);
            den += a;
            f32x2 av = {a, a};
            acc01 += av * h01;
            acc23 += av * h23;
        }
        if (hasB) {
            f32x2 h01, h23;
            h01.x = __uint_as_float(hvB.x << 16);
            h01.y = __uint_as_float(hvB.x & 0xffff0000u);
            h23.x = __uint_as_float(hvB.y << 16);
            h23.y = __uint_as_float(hvB.y & 0xffff0000u);
            f32x2 d2 = h01 * (f32x2){asv.x, asv.y} + h23 * (f32x2){asv.z, asv.w};
            float e = d2.x + d2.y + ednh;
            e = fmaxf(e, 0.2f * e);
            float a = __expf(e);
            den += a;
            f32x2 av = {a, a};
            acc01 += av * h01;
            acc23 += av * h23;
        }
        sA = sC; sB = sD; t = tn;
    }
    for (int off = 16; off >= 8; off >>= 1) {
        den      += __shfl_down(den, off, 32);
        acc01.x  += __shfl_down(acc01.x, off, 32);
        acc01.y  += __shfl_down(acc01.y, off, 32);
        acc23.x  += __shfl_down(acc23.x, off, 32);
        acc23.y  += __shfl_down(acc23.y, off, 32);
    }
    if (k == 0) {
        float inv = 1.f / (den + 1e-16f);
        float4 bv = *(const float4*)(prm + 32 + h * 4);
        float v0 = acc01.x * inv + bv.x;
        float v1 = acc01.y * inv + bv.y;
        float v2 = acc23.x * inv + bv.z;
        float v3 = acc23.y * inv + bv.w;
        v0 = (v0 > 0.f) ? v0 : expm1f(v0);
        v1 = (v1 > 0.f) ? v1 : expm1f(v1);
        v2 = (v2 > 0.f) ? v2 : expm1f(v2);
        v3 = (v3 > 0.f) ? v3 : expm1f(v3);
        *(float4*)(out + (size_t)n * SHD + h * 4) = make_float4(v0, v1, v2, v3);
    }
}

// ---------------- Temporal tail ----------------
// r16 post-mortem: VGPR=72 under launch_bounds(256,1) => the per-lane weight
// arrays were demoted to SCRATCH (global-backed) and re-read every step —
// ~100K stall cycles. Fix: NO local arrays in the recurrence; weights read
// directly from LDS as MAC operands (stride-21 lane addressing = conflict-
// free), 3-way split accumulators, __expf-based tanh.
__global__ __launch_bounds__(256, 1)
void k_tail(const void* trend, const void* seasonal, const void* residual,
                       const void* cv, const int* tgtp,
                       const void* tWih0, const void* tWhh0, const void* tbih0, const void* tbhh0,
                       const void* tWih1, const void* tWhh1, const void* tbih1, const void* tbhh1,
                       const void* sWih0, const void* sWhh0, const void* sbih0, const void* sbhh0,
                       const void* sWih1, const void* sWhh1, const void* sbih1, const void* sbhh1,
                       const void* res_W, const void* res_b,
                       const void* pg_W, const void* pg_b,
                       const void* f1_W, const void* f1_b,
                       const void* ln_g, const void* ln_b,
                       const void* f2_W, const void* f2_b,
                       const void* f3_W, const void* f3_b,
                       const int* flag, const float* A, void* out) {
    __shared__ float smem[11088];
    __shared__ float shh[2][24];
    __shared__ float sseq[2][SEQL][24];
    __shared__ float sx[2][SEQL];
    __shared__ float comb[97], gf[96], h1[64], h2s[32], stats[2];
    int tid = threadIdx.x;
    int f = flag[0];
    int w = tid >> 6, l = tid & 63;
    float* pk0a = smem;
    float* pk0b = smem + 1932;
    float* pk1a = smem + 3864;
    float* pk1b = smem + 7476;

    cp(pk0a, tWih0, 84, tid, 256, f);
    cp(pk0a + 84, tWhh0, 1764, tid, 256, f);
    cpsum(pk0a + 1848, tbih0, tbhh0, 84, tid, 256, f);
    cp(pk0b, sWih0, 84, tid, 256, f);
    cp(pk0b + 84, sWhh0, 1764, tid, 256, f);
    cpsum(pk0b + 1848, sbih0, sbhh0, 84, tid, 256, f);
    if (tid < 2 * SEQL) sx[tid / SEQL][tid % SEQL] = (tid < SEQL) ? ldw(trend, tid, f)
                                                                  : ldw(seasonal, tid - SEQL, f);
    if (tid < 48) shh[tid / 24][tid % 24] = 0.f;
    for (int i = tid; i < 2 * SEQL * 24; i += 256) ((float*)sseq)[i] = 0.f;
    __syncthreads();

    // ---- layer 0 (waves 0/1) | pk1 prefetch (waves 2/3) ----
    if (w < 2) {
        const float* P = (w == 0) ? pk0a : pk0b;
        float* SH = shh[w];
        int lb = (l < 20) ? (64 + l) : 83;          // clamped second row
        float kill = (l < 20) ? 1.f : 0.f;
        const float* ra = P + 84 + l * 21;          // Whh0 row l (LDS)
        const float* rb = P + 84 + lb * 21;
        float wa = P[l], ba = P[1848 + l];
        float wb = P[64 + (l < 20 ? l : 19)] * kill;
        float bb = P[1848 + 64 + (l < 20 ? l : 19)] * kill;
        float h = 0.f, c = 0.f;
#pragma unroll
        for (int t = 0; t < SEQL; t++) {
            float xt = sx[w][t];
            float a0 = ba + xt * wa, a1 = 0.f, a2 = 0.f;
            float b0 = bb + xt * wb, b1v = 0.f, b2 = 0.f;
#pragma unroll
            for (int j = 0; j < 21; j += 3) {
                float s0 = SH[j], s1 = SH[j + 1], s2 = SH[j + 2];
                a0 += s0 * ra[j]; a1 += s1 * ra[j + 1]; a2 += s2 * ra[j + 2];
                b0 += s0 * rb[j]; b1v += s1 * rb[j + 1]; b2 += s2 * rb[j + 2];
            }
            float acc_a = a0 + a1 + a2;
            float acc_b = (b0 + b1v + b2) * kill;
            float fj = __shfl(acc_a, 21 + l);
            float gj = __shfl(acc_a, 42 + l);
            float oa = __shfl(acc_a, 63);
            float ob = __shfl(acc_b, (l == 0) ? 0 : (l - 1));
            float oj = (l == 0) ? oa : ob;
            if (l < 21) {
                float iv = sigm(acc_a), fv = sigm(fj);
                float gv = tanh_fast(gj), ov = sigm(oj);
                c = fv * c + iv * gv;
                h = ov * tanh_fast(c);
                SH[l] = h;
                sseq[w][t][l] = h;
            }
        }
    } else {
        int t2 = tid - 128;
        cp(pk1a, tWih1, 1764, t2, 128, f);
        cp(pk1a + 1764, tWhh1, 1764, t2, 128, f);
        cpsum(pk1a + 3528, tbih1, tbhh1, 84, t2, 128, f);
        cp(pk1b, sWih1, 1764, t2, 128, f);
        cp(pk1b + 1764, sWhh1, 1764, t2, 128, f);
        cpsum(pk1b + 3528, sbih1, sbhh1, 84, t2, 128, f);
    }
    __syncthreads();
    if (tid < 48) shh[tid / 24][tid % 24] = 0.f;
    __syncthreads();

    // ---- layer 1 (waves 0/1) ----
    if (w < 2) {
        const float* P = (w == 0) ? pk1a : pk1b;
        float* SH = shh[w];
        int lb = (l < 20) ? (64 + l) : 83;
        float kill = (l < 20) ? 1.f : 0.f;
        const float* ua = P + l * 21;               // Wih1 row l
        const float* va = P + 1764 + l * 21;        // Whh1 row l
        const float* ub = P + lb * 21;
        const float* vb = P + 1764 + lb * 21;
        float ba = P[3528 + l];
        float bb = P[3528 + 64 + (l < 20 ? l : 19)] * kill;
        float h = 0.f, c = 0.f;
#pragma unroll
        for (int t = 0; t < SEQL; t++) {
            const float* XS = &sseq[w][t][0];
            float a0 = ba, a1 = 0.f, a2 = 0.f;
            float b0 = bb, b1v = 0.f, b2 = 0.f;
#pragma unroll
            for (int j = 0; j < 21; j += 3) {
                float x0 = XS[j], x1 = XS[j + 1], x2 = XS[j + 2];
                float s0 = SH[j], s1 = SH[j + 1], s2 = SH[j + 2];
                a0 += x0 * ua[j] + s0 * va[j];
                a1 += x1 * ua[j + 1] + s1 * va[j + 1];
                a2 += x2 * ua[j + 2] + s2 * va[j + 2];
                b0 += x0 * ub[j] + s0 * vb[j];
                b1v += x1 * ub[j + 1] + s1 * vb[j + 1];
                b2 += x2 * ub[j + 2] + s2 * vb[j + 2];
            }
            float acc_a = a0 + a1 + a2;
            float acc_b = (b0 + b1v + b2) * kill;
            float fj = __shfl(acc_a, 21 + l);
            float gj = __shfl(acc_a, 42 + l);
            float oa = __shfl(acc_a, 63);
            float ob = __shfl(acc_b, (l == 0) ? 0 : (l - 1));
            float oj = (l == 0) ? oa : ob;
            if (l < 21) {
                float iv = sigm(acc_a), fv = sigm(fj);
                float gv = tanh_fast(gj), ov = sigm(oj);
                c = fv * c + iv * gv;
                h = ov * tanh_fast(c);
                SH[l] = h;
            }
        }
        if (l < 21) comb[(w == 0 ? 32 : 53) + l] = h;
    }
    __syncthreads();

    // ---- fusion MLP (weights staged in LDS, aliasing dead LSTM packs) ----
    int tgt = tgtp[0];
    if (tid >= 64 && tid < 64 + TRH) {
        int j = tid - 64;
        float v = ldw(residual, SEQL - 1, f) * ldw(res_W, j, f) + ldw(res_b, j, f);
        comb[74 + j] = relu_nan(v);
    }
    if (tid >= 192 && tid < 192 + SHD) comb[tid - 192] = A[(size_t)tgt * SHD + (tid - 192)];
    if (tid == 90) comb[96] = ldw(cv, 0, f);
    cp(smem, pg_W, 97 * 96, tid, 256, f);
    __syncthreads();
    if (tid < 96) {
        float acc = ldw(pg_b, tid, f);
        for (int k2 = 0; k2 < 97; k2++) acc += comb[k2] * smem[k2 * 96 + tid];
        gf[tid] = comb[tid] * sigm(acc);
    }
    __syncthreads();
    cp(smem, f1_W, 96 * 64, tid, 256, f);
    __syncthreads();
    if (tid < 64) {
        float acc = ldw(f1_b, tid, f);
        for (int k2 = 0; k2 < 96; k2++) acc += gf[k2] * smem[k2 * 64 + tid];
        h1[tid] = acc;
    }
    __syncthreads();
    if (tid == 0) {
        float mu = 0.f;
        for (int j = 0; j < 64; j++) mu += h1[j];
        mu /= 64.f;
        float var = 0.f;
        for (int j = 0; j < 64; j++) { float d = h1[j] - mu; var += d * d; }
        var /= 64.f;
        stats[0] = mu; stats[1] = rsqrtf(var + 1e-5f);
    }
    cp(smem, f2_W, 64 * 32, tid, 256, f);
    cp(smem + 64 * 32, f3_W, 32 * 14, tid, 256, f);
    __syncthreads();
    if (tid < 64) {
        float v = (h1[tid] - stats[0]) * stats[1] * ldw(ln_g, tid, f) + ldw(ln_b, tid, f);
        h1[tid] = relu_nan(v);
    }
    __syncthreads();
    if (tid < 32) {
        float acc = ldw(f2_b, tid, f);
        for (int k2 = 0; k2 < 64; k2++) acc += h1[k2] * smem[k2 * 32 + tid];
        h2s[tid] = relu_nan(acc);
    }
    __syncthreads();
    if (tid < 14) {
        float acc = ldw(f3_b, tid, f);
        for (int k2 = 0; k2 < 32; k2++) acc += h2s[k2] * smem[64 * 32 + k2 * 14 + tid];
        if (acc != acc) acc = 3333.0f;
        if (f) ((float*)out)[tid] = acc;
        else   ((bf16*)out)[tid] = __float2bfloat16(acc);
    }
}

// ---------------- host helpers ----------------
static inline unsigned short h_f2bf(float f) {
    union { float f; unsigned u; } x; x.f = f;
    return (unsigned short)(x.u >> 16);
}
static unsigned short g_diag[SEQL];

// ---------------- launch ----------------
extern "C" void kernel_launch(void* const* d_in, const int* in_sizes, int n_in,
                              void* d_out, int out_size, void* d_ws, size_t ws_size,
                              hipStream_t stream) {
    const int* ei  = (const int*)d_in[1];
    const int* tgt = (const int*)d_in[6];

    const size_t HWB  = sizeof(unsigned short) * (size_t)NN * SHD;
    const size_t EDB  = sizeof(float) * (size_t)NN * NH;
    const size_t AB   = sizeof(float) * (size_t)NN * SHD;
    const size_t CSRB = sizeof(int) * (size_t)NBUK * CAP;
    const size_t NEED = 256 + 1024 + sizeof(int) * (size_t)(NC + NBUK + 2 * NN + 32)
                      + CSRB + 512 + HWB + EDB + AB;
    if (ws_size < NEED ||
        sizeof(int) * (size_t)NC * CAPG1 > CSRB ||
        sizeof(int) * (size_t)NBUK * CAP > HWB + EDB + AB) {
        for (int i = 0; i < SEQL; i++) g_diag[i] = h_f2bf(7777.0f);
        hipMemcpyAsync(d_out, g_diag, SEQL * sizeof(unsigned short),
                       hipMemcpyHostToDevice, stream);
        return;
    }

    char* p = (char*)d_ws;
    int*   flag = (int*)p;   p += 256;
    float* prm  = (float*)p; p += 1024;
    int* g1     = (int*)p; p += sizeof(int) * NC;
    int* g2     = (int*)p; p += sizeof(int) * NBUK;
    int* rstart = (int*)p; p += sizeof(int) * NN;
    int* rdeg   = (int*)p; p += sizeof(int) * (NN + 32);
    int* csr    = (int*)p; p += CSRB;
    p = (char*)(((uintptr_t)p + 255) & ~(uintptr_t)255);
    unsigned short* hWb = (unsigned short*)p; p += HWB;
    float* ed = (float*)p; p += EDB;
    float* A  = (float*)p; p += AB;
    int* rec1 = csr;
    int* rec2 = (int*)hWb;

    dim3 b256(256);
    dim3 gN((NN + 255) / 256);
    dim3 gA2(((NN + 1) / 2 * 64 + 255) / 256);

    PatternAwareSTGAT_94489281309_kernel<<<dim3(1), dim3(64), 0, stream>>>(
        (const unsigned int*)d_in[0], flag,
        d_in[8], d_in[10], d_in[12], d_in[14], d_in[16], d_in[18], prm);

    hipMemsetAsync(g1, 0, sizeof(int) * (NC + NBUK), stream);
    k_p1<<<dim3(NBC1), b256, 0, stream>>>(ei, g1, rec1);
    k_p2<<<dim3(NC * PB2), b256, 0, stream>>>(rec1, g1, g2, rec2);
    k_build<<<dim3(NBUK), b256, 0, stream>>>(rec2, g2, csr, rstart, rdeg);

    k_transform0<<<gN, b256, 0, stream>>>(d_in[0], d_in[7], d_in[9], flag, hWb, ed);
    k_aggregate<<<gA2, b256, 0, stream>>>(rstart, rdeg, csr, hWb, ed, prm, A);
    k_transform1<<<gN, b256, 0, stream>>>(A, d_in[11], d_in[13], flag, hWb, ed);
    k_aggregate<<<gA2, b256, 0, stream>>>(rstart, rdeg, csr, hWb, ed, prm + 64, A);
    k_transform1<<<gN, b256, 0, stream>>>(A, d_in[15], d_in[17], flag, hWb, ed);
    k_aggregate<<<gA2, b256, 0, stream>>>(rstart, rdeg, csr, hWb, ed, prm + 128, A);

    k_tail<<<dim3(1), b256, 0, stream>>>(
        d_in[2], d_in[3], d_in[4], d_in[5], tgt,
        d_in[19], d_in[20], d_in[21], d_in[22],
        d_in[23], d_in[24], d_in[25], d_in[26],
        d_in[27], d_in[28], d_in[29], d_in[30],
        d_in[31], d_in[32], d_in[33], d_in[34],
        d_in[35], d_in[36],
        d_in[37], d_in[38],
        d_in[39], d_in[40],
        d_in[41], d_in[42],
        d_in[43], d_in[44],
        d_in[45], d_in[46],
        flag, A, d_out);
}